// Round 10
// baseline (881.544 us; speedup 1.0000x reference)
//
#include <hip/hip_runtime.h>
#include <hip/hip_bf16.h>
#include <math.h>

// ---------------------------------------------------------------------------
// Problem constants
// ---------------------------------------------------------------------------
#define B_SZ 8
#define L_SZ 1024
#define DM 512          // d_model
#define DFF 2048        // d_ff
#define DIN 1024        // expand * d_model
#define DSTATE 16
#define DTRANK 32
#define MROWS (B_SZ * L_SZ)   // 8192
#define CH 256                // scan chunk length
#define NCH 4                 // chunks per sequence

typedef __hip_bfloat16 bf16;
typedef unsigned short u16;
using f32x4 = __attribute__((ext_vector_type(4))) float;
using bfrag = __attribute__((ext_vector_type(8))) short;   // 8 bf16 = 4 VGPR

__device__ inline float ldf(const float* p, long i) { return p[i]; }
__device__ inline float ldf(const bf16* p, long i) {
  return __uint_as_float((unsigned)((const u16*)p)[i] << 16);
}
__device__ inline void stf(float* p, long i, float v) { p[i] = v; }
__device__ inline void stf(bf16* p, long i, float v) { p[i] = __float2bfloat16(v); }
__device__ inline float b2f(u16 x) {
  return __uint_as_float((unsigned)x << 16);
}
__device__ inline u16 f2b(float v) {
  union { bf16 h; u16 u; } c;
  c.h = __float2bfloat16(v);
  return c.u;
}

// Raw v_exp_f32: computes 2^x in one trans-pipe instruction.
__device__ inline float fexp2(float x) {
  float r;
  asm("v_exp_f32 %0, %1" : "=v"(r) : "v"(x));
  return r;
}

// Async global->LDS, 16B per lane. LDS dest is wave-uniform base + lane*16;
// global source is per-lane. Compiler emits vmcnt(0) before s_barrier, so
// __syncthreads() after issuing guarantees completion (m97 pattern).
typedef __attribute__((address_space(1))) const void g_void;
typedef __attribute__((address_space(3))) void l_void;
__device__ inline void gl_lds16(const void* g, void* l) {
  __builtin_amdgcn_global_load_lds((g_void*)g, (l_void*)l, 16, 0, 0);
}

// B-element loader (4 consecutive): fp32 direct, bf16 convert.
__device__ inline float4 ld4f_bt(const float* p) { return *(const float4*)p; }
__device__ inline float4 ld4f_bt(const bf16* p) {
  ushort4 u = *(const ushort4*)p;
  float4 v;
  v.x = b2f(u.x); v.y = b2f(u.y); v.z = b2f(u.z); v.w = b2f(u.w);
  return v;
}

// 16-element row loader into packed bf16 (2 x uint4), fp32 src (RNE convert).
__device__ inline void ld16f(const float* p, uint4& lo, uint4& hi) {
  float4 a = *(const float4*)p, b = *(const float4*)(p + 4);
  float4 c = *(const float4*)(p + 8), d = *(const float4*)(p + 12);
  union { uint4 v; u16 s[8]; } L, H;
  L.s[0] = f2b(a.x); L.s[1] = f2b(a.y); L.s[2] = f2b(a.z); L.s[3] = f2b(a.w);
  L.s[4] = f2b(b.x); L.s[5] = f2b(b.y); L.s[6] = f2b(b.z); L.s[7] = f2b(b.w);
  H.s[0] = f2b(c.x); H.s[1] = f2b(c.y); H.s[2] = f2b(c.z); H.s[3] = f2b(c.w);
  H.s[4] = f2b(d.x); H.s[5] = f2b(d.y); H.s[6] = f2b(d.z); H.s[7] = f2b(d.w);
  lo = L.v; hi = H.v;
}

// Fused DPP rotate-add reduce within 16-lane row.
__device__ inline float dpp_add_r8(float x) {
  float r; asm("v_add_f32 %0, %1, %2 row_ror:8" : "=v"(r) : "v"(x), "v"(x)); return r;
}
__device__ inline float dpp_add_r4(float x) {
  float r; asm("v_add_f32 %0, %1, %2 row_ror:4" : "=v"(r) : "v"(x), "v"(x)); return r;
}
__device__ inline float dpp_add_r2(float x) {
  float r; asm("v_add_f32 %0, %1, %2 row_ror:2" : "=v"(r) : "v"(x), "v"(x)); return r;
}
__device__ inline float dpp_add_r1(float x) {
  float r; asm("v_add_f32 %0, %1, %2 row_ror:1" : "=v"(r) : "v"(x), "v"(x)); return r;
}
__device__ inline float row16_sum(float x) {
  return dpp_add_r1(dpp_add_r2(dpp_add_r4(dpp_add_r8(x))));
}

__device__ inline int flipL(int r) {
  int t = r & (L_SZ - 1);
  return (r - t) + (L_SZ - 1 - t);
}

// ---------------------------------------------------------------------------
// Consolidated fp32 -> bf16 weight conversion: 8 segments, one dispatch.
// Segs 0-5: 524288 elems (2048 blocks each); segs 6-7: 1048576 (4096 blocks).
// Also builds the combined [W1;W2] layouts for the merged xs/gate GEMMs.
// ---------------------------------------------------------------------------
__global__ __launch_bounds__(256) void cvt8_k(
    const float* s0, const float* s1, const float* s2, const float* s3,
    const float* s4, const float* s5, const float* s6, const float* s7,
    bf16* d0, bf16* d1, bf16* d2, bf16* d3,
    bf16* d4, bf16* d5, bf16* d6, bf16* d7) {
  int blk = blockIdx.x;
  const float* s; bf16* d; long off;
  if (blk < 2048)       { s = s0; d = d0; off = (long)blk * 256; }
  else if (blk < 4096)  { s = s1; d = d1; off = (long)(blk - 2048) * 256; }
  else if (blk < 6144)  { s = s2; d = d2; off = (long)(blk - 4096) * 256; }
  else if (blk < 8192)  { s = s3; d = d3; off = (long)(blk - 6144) * 256; }
  else if (blk < 10240) { s = s4; d = d4; off = (long)(blk - 8192) * 256; }
  else if (blk < 12288) { s = s5; d = d5; off = (long)(blk - 10240) * 256; }
  else if (blk < 16384) { s = s6; d = d6; off = (long)(blk - 12288) * 256; }
  else                  { s = s7; d = d7; off = (long)(blk - 16384) * 256; }
  off += threadIdx.x;
  d[off] = __float2bfloat16(s[off]);
}

// ---------------------------------------------------------------------------
// bf16 MFMA GEMM: C(M,N) = A(M,K) @ W(N,K)^T, fp32 accumulate.
// 128x128 tile, BK=32, 4 waves, each 64x64 via 4x4 v_mfma_f32_16x16x32_bf16.
// W staged via global_load_lds width=16. A: bf16 -> gload_lds; fp32 ->
// inline-convert register path. LDS sized per-path via constexpr.
//
// Merged epilogues (halve x reads + dispatches for direction pairs):
//  STORE2: cols < DIN -> C[row]; cols >= DIN -> C2[flipL(row)][col-DIN]
//  GATE2:  same routing, y *= silu(acc) in place.
// ---------------------------------------------------------------------------
constexpr int MEPI_STORE2 = 0;
constexpr int MEPI_GATE2 = 1;
constexpr int MEPI_BIAS_GELU = 2;   // bf16 out
constexpr int MEPI_BIAS_RES = 3;    // fp32 out = acc + bias + res

template <int EPI, typename TA, typename TO>
__global__ __launch_bounds__(256) void mgemm_k(
    const TA* __restrict__ Ab, int lda,
    const bf16* __restrict__ Wb, int ldw,
    TO* __restrict__ C, TO* __restrict__ C2, int ldc,
    const float* __restrict__ bias,
    const float* __restrict__ res,
    int K) {
  constexpr bool ABF = (sizeof(TA) == 2);   // bf16 A -> gload_lds path
  __shared__ u16 Wsm[128][32];
  __shared__ u16 AsmL[ABF ? 128 : 1][32];
  __shared__ u16 AsmP[ABF ? 1 : 128][ABF ? 1 : 40];
  const int tid = threadIdx.x;
  const int m0 = blockIdx.y * 128;
  const int n0 = blockIdx.x * 128;

  // --- gload_lds staging geometry (W always; A when ABF) ---
  const int srow4 = tid >> 2;          // 0..63
  const int q16 = tid & 3;             // 16B chunk in row
  const u16* Wg0 = (const u16*)Wb + (long)(n0 + srow4) * ldw + q16 * 8;
  const u16* Wg1 = (const u16*)Wb + (long)(n0 + 64 + srow4) * ldw + q16 * 8;
  char* WsmB = (char*)&Wsm[0][0] + (tid >> 6) * 1024;   // wave-uniform

  const u16* Ag0 = (const u16*)Ab + (long)(m0 + srow4) * lda + q16 * 8;
  const u16* Ag1 = (const u16*)Ab + (long)(m0 + 64 + srow4) * lda + q16 * 8;
  char* AsmB = (char*)&AsmL[0][0] + (tid >> 6) * 1024;

  // --- fp32-A register staging geometry ---
  const int srow = tid >> 1;
  const int scol = (tid & 1) * 16;
  const TA* Agf = Ab + (long)(m0 + srow) * lda + scol;

  const int lane = tid & 63, quad = lane >> 4, l16 = lane & 15;
  const int wid = tid >> 6;
  const int wm = (wid & 1) * 64, wn = (wid >> 1) * 64;

  f32x4 acc[4][4];
#pragma unroll
  for (int i = 0; i < 4; ++i)
#pragma unroll
    for (int j = 0; j < 4; ++j) acc[i][j] = {0.f, 0.f, 0.f, 0.f};

  for (int k0 = 0; k0 < K; k0 += 32) {
    uint4 av0, av1;
    if constexpr (!ABF) ld16f((const float*)(Agf + k0), av0, av1);
    __syncthreads();   // previous iteration's frag reads complete
    gl_lds16(Wg0 + k0, WsmB);
    gl_lds16(Wg1 + k0, WsmB + 4096);
    if constexpr (ABF) {
      gl_lds16(Ag0 + k0, AsmB);
      gl_lds16(Ag1 + k0, AsmB + 4096);
    } else {
      *(uint4*)&AsmP[srow][scol] = av0;
      *(uint4*)&AsmP[srow][scol + 8] = av1;
    }
    __syncthreads();   // vmcnt(0)+lgkmcnt(0) drained before barrier
    bfrag a[4], b[4];
#pragma unroll
    for (int mi = 0; mi < 4; ++mi) {
      if constexpr (ABF)
        a[mi] = *(const bfrag*)&AsmL[wm + mi * 16 + l16][quad * 8];
      else
        a[mi] = *(const bfrag*)&AsmP[wm + mi * 16 + l16][quad * 8];
    }
#pragma unroll
    for (int ni = 0; ni < 4; ++ni)
      b[ni] = *(const bfrag*)&Wsm[wn + ni * 16 + l16][quad * 8];
#pragma unroll
    for (int mi = 0; mi < 4; ++mi)
#pragma unroll
      for (int ni = 0; ni < 4; ++ni)
        acc[mi][ni] = __builtin_amdgcn_mfma_f32_16x16x32_bf16(
            a[mi], b[ni], acc[mi][ni], 0, 0, 0);
  }

  const bool second = (n0 >= DIN);   // block-uniform (128 | DIN)
#pragma unroll
  for (int mi = 0; mi < 4; ++mi)
#pragma unroll
    for (int ni = 0; ni < 4; ++ni)
#pragma unroll
      for (int r = 0; r < 4; ++r) {
        int row = m0 + wm + mi * 16 + quad * 4 + r;
        int col = n0 + wn + ni * 16 + l16;
        float v = acc[mi][ni][r];
        if (EPI == MEPI_STORE2) {
          if (second) stf(C2, (long)flipL(row) * ldc + (col - DIN), v);
          else stf(C, (long)row * ldc + col, v);
        } else if (EPI == MEPI_GATE2) {
          TO* T = second ? C2 : C;
          long oi = second ? ((long)flipL(row) * ldc + (col - DIN))
                           : ((long)row * ldc + col);
          float y = ldf((const bf16*)T, oi);
          float sz = v / (1.f + __expf(-v));
          stf(T, oi, y * sz);
        } else if (EPI == MEPI_BIAS_GELU) {
          long oi = (long)row * ldc + col;
          v += bias[col];
          v = 0.5f * v * (1.f + erff(v * 0.70710678118654752440f));
          stf(C, oi, v);
        } else if (EPI == MEPI_BIAS_RES) {
          long oi = (long)row * ldc + col;
          ((float*)C)[oi] = v + bias[col] + res[oi];
        }
      }
}

// ---------------------------------------------------------------------------
// MFMA merge: newx(M,DM) = y1 @ W1^T + flip_L(y2) @ W2^T + xres (fp32 out).
// Both operands bf16 -> full gload_lds staging.
// ---------------------------------------------------------------------------
__global__ __launch_bounds__(256) void mmerge_k(
    const bf16* __restrict__ y1, const bf16* __restrict__ y2,
    const bf16* __restrict__ W1, const bf16* __restrict__ W2,
    const float* __restrict__ xres, float* __restrict__ newx) {
  __shared__ u16 AsmL[128][32];
  __shared__ u16 Wsm[128][32];
  const int tid = threadIdx.x;
  const int m0 = blockIdx.y * 128;
  const int n0 = blockIdx.x * 128;

  const int srow4 = tid >> 2;
  const int q16 = tid & 3;
  int r1a = m0 + srow4, r1b = m0 + 64 + srow4;
  int r2a = flipL(r1a), r2b = flipL(r1b);
  const u16* A1g0 = (const u16*)y1 + (long)r1a * DIN + q16 * 8;
  const u16* A1g1 = (const u16*)y1 + (long)r1b * DIN + q16 * 8;
  const u16* A2g0 = (const u16*)y2 + (long)r2a * DIN + q16 * 8;
  const u16* A2g1 = (const u16*)y2 + (long)r2b * DIN + q16 * 8;
  const u16* W1g0 = (const u16*)W1 + (long)(n0 + srow4) * DIN + q16 * 8;
  const u16* W1g1 = (const u16*)W1 + (long)(n0 + 64 + srow4) * DIN + q16 * 8;
  const u16* W2g0 = (const u16*)W2 + (long)(n0 + srow4) * DIN + q16 * 8;
  const u16* W2g1 = (const u16*)W2 + (long)(n0 + 64 + srow4) * DIN + q16 * 8;
  char* AsmB = (char*)&AsmL[0][0] + (tid >> 6) * 1024;
  char* WsmB = (char*)&Wsm[0][0] + (tid >> 6) * 1024;

  const int lane = tid & 63, quad = lane >> 4, l16 = lane & 15;
  const int wid = tid >> 6;
  const int wm = (wid & 1) * 64, wn = (wid >> 1) * 64;

  f32x4 acc[4][4];
#pragma unroll
  for (int i = 0; i < 4; ++i)
#pragma unroll
    for (int j = 0; j < 4; ++j) acc[i][j] = {0.f, 0.f, 0.f, 0.f};

  for (int k0 = 0; k0 < 2 * DIN; k0 += 32) {
    const bool ph2 = (k0 >= DIN);
    const int kk = k0 & (DIN - 1);
    const u16* a0 = ph2 ? A2g0 : A1g0;
    const u16* a1 = ph2 ? A2g1 : A1g1;
    const u16* w0 = ph2 ? W2g0 : W1g0;
    const u16* w1 = ph2 ? W2g1 : W1g1;
    __syncthreads();
    gl_lds16(a0 + kk, AsmB);
    gl_lds16(a1 + kk, AsmB + 4096);
    gl_lds16(w0 + kk, WsmB);
    gl_lds16(w1 + kk, WsmB + 4096);
    __syncthreads();
    bfrag a[4], b[4];
#pragma unroll
    for (int mi = 0; mi < 4; ++mi)
      a[mi] = *(const bfrag*)&AsmL[wm + mi * 16 + l16][quad * 8];
#pragma unroll
    for (int ni = 0; ni < 4; ++ni)
      b[ni] = *(const bfrag*)&Wsm[wn + ni * 16 + l16][quad * 8];
#pragma unroll
    for (int mi = 0; mi < 4; ++mi)
#pragma unroll
      for (int ni = 0; ni < 4; ++ni)
        acc[mi][ni] = __builtin_amdgcn_mfma_f32_16x16x32_bf16(
            a[mi], b[ni], acc[mi][ni], 0, 0, 0);
  }

#pragma unroll
  for (int mi = 0; mi < 4; ++mi)
#pragma unroll
    for (int ni = 0; ni < 4; ++ni)
#pragma unroll
      for (int r = 0; r < 4; ++r) {
        int row = m0 + wm + mi * 16 + quad * 4 + r;
        int col = n0 + wn + ni * 16 + l16;
        long oi = (long)row * DM + col;
        newx[oi] = acc[mi][ni][r] + xres[oi];
      }
}

// ---------------------------------------------------------------------------
// Vector-ALU GEMM with ROW-MAJOR B: C(M,N) = A(M,K) @ B(K,N).
// Used only for dtT now (K=32, 2048 blocks -> well occupied).
// ---------------------------------------------------------------------------
constexpr int EPI_NONE = 0;
constexpr int EPI_SOFTPLUS_ROW = 1;

#define BM 64
#define BN 64
#define BKK 16

template <int EPI, typename TB, typename TO>
__global__ __launch_bounds__(256) void gemmBT_k(
    const float* __restrict__ A,
    const TB* __restrict__ B,
    TO* __restrict__ C, int N,
    const float* __restrict__ bias, int K) {
  __shared__ float As[BKK][BM + 4];
  __shared__ float Bs[BKK][BN + 4];
  const int tid = threadIdx.x;
  const int m0 = blockIdx.y * BM;
  const int n0 = blockIdx.x * BN;
  const int tx = tid & 15;
  const int ty = tid >> 4;
  const int lrow = tid >> 2;
  const int lcol = (tid & 3) * 4;
  const int kr = tid >> 4;
  const int nc = (tid & 15) * 4;

  const float* Arow = A + (long)(m0 + lrow) * K;

  float acc[4][4] = {};
  for (int k0 = 0; k0 < K; k0 += BKK) {
    float4 av = *(const float4*)(Arow + k0 + lcol);
    float4 bv = ld4f_bt(B + (long)(k0 + kr) * N + n0 + nc);
    As[lcol + 0][lrow] = av.x; As[lcol + 1][lrow] = av.y;
    As[lcol + 2][lrow] = av.z; As[lcol + 3][lrow] = av.w;
    Bs[kr][nc + 0] = bv.x; Bs[kr][nc + 1] = bv.y;
    Bs[kr][nc + 2] = bv.z; Bs[kr][nc + 3] = bv.w;
    __syncthreads();
#pragma unroll
    for (int k = 0; k < BKK; ++k) {
      float a[4], b[4];
#pragma unroll
      for (int i = 0; i < 4; ++i) a[i] = As[k][ty * 4 + i];
#pragma unroll
      for (int j = 0; j < 4; ++j) b[j] = Bs[k][tx * 4 + j];
#pragma unroll
      for (int i = 0; i < 4; ++i)
#pragma unroll
        for (int j = 0; j < 4; ++j) acc[i][j] += a[i] * b[j];
    }
    __syncthreads();
  }

#pragma unroll
  for (int i = 0; i < 4; ++i) {
    int r = m0 + ty * 4 + i;
#pragma unroll
    for (int j = 0; j < 4; ++j) {
      int c = n0 + tx * 4 + j;
      float v = acc[i][j];
      if (EPI == EPI_SOFTPLUS_ROW) {
        v += bias[r];
        v = (v > 20.f) ? v : log1pf(__expf(v));
      }
      stf(C, (long)r * N + c, v);
    }
  }
}

// ---------------------------------------------------------------------------
// R10: split-K x-projection, both directions in ONE dispatch.
// C(64 x 8192) = xp_w(64 x 1024) @ xcT(1024 x 8192), fp32 out via atomicAdd.
// Old form was 128 blocks (0.5 block/CU, 1 wave/SIMD -> exposed LDS latency,
// est. 50-120us each). Grid (128 N-tiles, 8 K-slices, 2 dirs) = 2048 blocks
// (8/CU): K-slice = 128, each block computes a 64x64 partial and atomically
// accumulates. xdT must be zeroed first (hipMemsetAsync).
// ---------------------------------------------------------------------------
__global__ __launch_bounds__(256) void xprojs_k(
    const float* __restrict__ A1, const bf16* __restrict__ B1,
    float* __restrict__ C1,
    const float* __restrict__ A2, const bf16* __restrict__ B2,
    float* __restrict__ C2) {
  __shared__ float As[BKK][BM + 4];
  __shared__ float Bs[BKK][BN + 4];
  const int tid = threadIdx.x;
  const int n0 = blockIdx.x * BN;
  const int kbeg = blockIdx.y * 128;
  const int dir = blockIdx.z;
  const float* A = dir ? A2 : A1;
  const bf16* Bm = dir ? B2 : B1;
  float* C = dir ? C2 : C1;
  const int N = MROWS, K = DIN;
  const int tx = tid & 15;
  const int ty = tid >> 4;
  const int lrow = tid >> 2;        // m index 0..63 (BM=64 covers all M)
  const int lcol = (tid & 3) * 4;
  const int kr = tid >> 4;
  const int nc = (tid & 15) * 4;

  const float* Arow = A + (long)lrow * K;

  float acc[4][4] = {};
  for (int k0 = kbeg; k0 < kbeg + 128; k0 += BKK) {
    float4 av = *(const float4*)(Arow + k0 + lcol);
    float4 bv = ld4f_bt(Bm + (long)(k0 + kr) * N + n0 + nc);
    As[lcol + 0][lrow] = av.x; As[lcol + 1][lrow] = av.y;
    As[lcol + 2][lrow] = av.z; As[lcol + 3][lrow] = av.w;
    Bs[kr][nc + 0] = bv.x; Bs[kr][nc + 1] = bv.y;
    Bs[kr][nc + 2] = bv.z; Bs[kr][nc + 3] = bv.w;
    __syncthreads();
#pragma unroll
    for (int k = 0; k < BKK; ++k) {
      float a[4], b[4];
#pragma unroll
      for (int i = 0; i < 4; ++i) a[i] = As[k][ty * 4 + i];
#pragma unroll
      for (int j = 0; j < 4; ++j) b[j] = Bs[k][tx * 4 + j];
#pragma unroll
      for (int i = 0; i < 4; ++i)
#pragma unroll
        for (int j = 0; j < 4; ++j) acc[i][j] += a[i] * b[j];
    }
    __syncthreads();
  }

#pragma unroll
  for (int i = 0; i < 4; ++i) {
    int r = ty * 4 + i;
#pragma unroll
    for (int j = 0; j < 4; ++j) {
      int c = n0 + tx * 4 + j;
      atomicAdd(&C[(long)r * N + c], acc[i][j]);
    }
  }
}

// ---------------------------------------------------------------------------
// Fused depthwise causal conv (k=4) + bias + silu + TRANSPOSE.
// ---------------------------------------------------------------------------
__global__ __launch_bounds__(256) void convT_k(
    const bf16* __restrict__ xs, const float* __restrict__ w,
    const float* __restrict__ b, bf16* __restrict__ xcT) {
  __shared__ u16 T[64][72];
  int c0 = blockIdx.x * 64;
  int r0 = blockIdx.y * 64;
  int tid = threadIdx.x;
  int tr = tid >> 2;
  int tc = (tid & 3) * 16;

  const u16* src = (const u16*)xs + (long)(r0 + tr) * DIN + c0 + tc;
  uint4 v0 = *(const uint4*)src;
  uint4 v1 = *(const uint4*)(src + 8);
  u16 tmp[16];
  *(uint4*)tmp = v0;
  *(uint4*)(tmp + 8) = v1;
#pragma unroll
  for (int j = 0; j < 16; ++j) T[tc + j][tr + 3] = tmp[j];
  bool head = (r0 & (L_SZ - 1)) == 0;
  if (tid < 12) {
    int hr = tid >> 2;
    int seg = (tid & 3) * 16;
    if (head) {
#pragma unroll
      for (int j = 0; j < 16; ++j) T[seg + j][hr] = 0;
    } else {
      const u16* hs = (const u16*)xs + (long)(r0 - 3 + hr) * DIN + c0 + seg;
      uint4 h0 = *(const uint4*)hs;
      uint4 h1 = *(const uint4*)(hs + 8);
      u16 ht[16];
      *(uint4*)ht = h0;
      *(uint4*)(ht + 8) = h1;
#pragma unroll
      for (int j = 0; j < 16; ++j) T[seg + j][hr] = ht[j];
    }
  }
  __syncthreads();

  int d = c0 + tr;
  float w0 = w[d * 4 + 0], w1 = w[d * 4 + 1], w2 = w[d * 4 + 2], w3 = w[d * 4 + 3];
  float bd = b[d];
  float X[19];
#pragma unroll
  for (int k = 0; k < 19; ++k) X[k] = b2f(T[tr][tc + k]);
  u16 o[16];
#pragma unroll
  for (int j = 0; j < 16; ++j) {
    float acc = bd + w0 * X[j] + w1 * X[j + 1] + w2 * X[j + 2] + w3 * X[j + 3];
    o[j] = f2b(acc / (1.f + __expf(-acc)));
  }
  u16* dst = (u16*)xcT + (long)d * MROWS + r0 + tc;
  *(uint4*)dst = *(uint4*)o;
  *(uint4*)(dst + 8) = *(uint4*)(o + 8);
}

// ---------------------------------------------------------------------------
// Chunked bidirectional selective scan, 4 d-channels per thread (R7, proven:
// 306 -> 136us; per-CU request-rate was the limit, B/C loads shared over 4 d).
// ---------------------------------------------------------------------------
__global__ __launch_bounds__(256, 4) void scan1_k(
    const u16* __restrict__ dtT1, const u16* __restrict__ dtT2,
    const u16* __restrict__ uT1, const u16* __restrict__ uT2,
    const float* __restrict__ xd1, const float* __restrict__ xd2,
    const float* __restrict__ Alog1, const float* __restrict__ Alog2,
    bf16* __restrict__ hl1, bf16* __restrict__ hl2,
    float* __restrict__ sd1, float* __restrict__ sd2) {
  int blk = blockIdx.x;
  int dblk = blk & 15;
  int r = blk >> 4;
  int c = r % 3; r /= 3;
  int b = r & 7;
  int dir = r >> 3;
  int tid = threadIdx.x;
  int s = tid & 15;
  int gi = tid >> 4;
  int d0 = dblk * 64 + gi * 4;
  const u16* dtT = dir ? dtT2 : dtT1;
  const u16* uT = dir ? uT2 : uT1;
  const float* xd = dir ? xd2 : xd1;
  const float* Alog = dir ? Alog2 : Alog1;
  bf16* hl = dir ? hl2 : hl1;
  float* sd = dir ? sd2 : sd1;

  float A2[4], h[4], sdt[4];
#pragma unroll
  for (int dd = 0; dd < 4; ++dd) {
    A2[dd] = -__expf(Alog[(d0 + dd) * DSTATE + s]) * 1.4426950408889634f;
    h[dd] = 0.f;
    sdt[dd] = 0.f;
  }
  long t0 = (long)b * L_SZ + c * CH;
  const u16* pdt = dtT + (long)d0 * MROWS + t0;
  const u16* pu = uT + (long)d0 * MROWS + t0;
  const float* pB = xd + (long)(DTRANK + s) * MROWS + t0;

  for (int g = 0; g < CH / 8; ++g) {
    union { uint4 v; u16 a[8]; } dt8[4], u8[4];
    union { float4 v[2]; float a[8]; } B8;
#pragma unroll
    for (int dd = 0; dd < 4; ++dd) {
      dt8[dd].v = *(const uint4*)(pdt + (long)dd * MROWS + g * 8);
      u8[dd].v = *(const uint4*)(pu + (long)dd * MROWS + g * 8);
    }
    B8.v[0] = *(const float4*)(pB + g * 8);
    B8.v[1] = *(const float4*)(pB + g * 8 + 4);
#pragma unroll
    for (int j = 0; j < 8; ++j) {
      float Bj = B8.a[j];
#pragma unroll
      for (int dd = 0; dd < 4; ++dd) {
        float dtv = b2f(dt8[dd].a[j]);
        float uv = b2f(u8[dd].a[j]);
        float da = fexp2(dtv * A2[dd]);
        h[dd] = da * h[dd] + (dtv * uv) * Bj;
        sdt[dd] += dtv;
      }
    }
  }
#pragma unroll
  for (int dd = 0; dd < 4; ++dd) {
    int ci = (b * 3 + c) * 1024 + d0 + dd;
    hl[(long)ci * 16 + s] = __float2bfloat16(h[dd]);
    if (s == 0) sd[ci] = sdt[dd];
  }
}

__global__ __launch_bounds__(256, 4) void scan2_k(
    const u16* __restrict__ dtT1, const u16* __restrict__ dtT2,
    const u16* __restrict__ uT1, const u16* __restrict__ uT2,
    const float* __restrict__ xd1, const float* __restrict__ xd2,
    const float* __restrict__ Alog1, const float* __restrict__ Alog2,
    const float* __restrict__ D1, const float* __restrict__ D2,
    const bf16* __restrict__ hl1, const bf16* __restrict__ hl2,
    const float* __restrict__ sd1, const float* __restrict__ sd2,
    bf16* __restrict__ y1, bf16* __restrict__ y2) {
  int blk = blockIdx.x;
  int dblk = blk & 15;
  int c = (blk >> 4) & 3;
  int b = (blk >> 6) & 7;
  int dir = blk >> 9;
  int tid = threadIdx.x;
  int s = tid & 15;
  int gi = tid >> 4;
  int d0 = dblk * 64 + gi * 4;
  const u16* dtT = dir ? dtT2 : dtT1;
  const u16* uT = dir ? uT2 : uT1;
  const float* xd = dir ? xd2 : xd1;
  const float* Alog = dir ? Alog2 : Alog1;
  const float* Dp = dir ? D2 : D1;
  const bf16* hl = dir ? hl2 : hl1;
  const float* sd = dir ? sd2 : sd1;
  bf16* out = dir ? y2 : y1;

  float A2[4], h[4], Dd[4];
#pragma unroll
  for (int dd = 0; dd < 4; ++dd) {
    A2[dd] = -__expf(Alog[(d0 + dd) * DSTATE + s]) * 1.4426950408889634f;
    Dd[dd] = Dp[d0 + dd];
    h[dd] = 0.f;
  }

  for (int cc = 0; cc < c; ++cc) {
#pragma unroll
    for (int dd = 0; dd < 4; ++dd) {
      int ci = (b * 3 + cc) * 1024 + d0 + dd;
      float P = fexp2(A2[dd] * sd[ci]);
      h[dd] = h[dd] * P + b2f(((const u16*)hl)[(long)ci * 16 + s]);
    }
  }

  long t0 = (long)b * L_SZ + c * CH;
  const u16* pdt = dtT + (long)d0 * MROWS + t0;
  const u16* pu = uT + (long)d0 * MROWS + t0;
  const float* pB = xd + (long)(DTRANK + s) * MROWS + t0;
  const float* pC = xd + (long)(DTRANK + DSTATE + s) * MROWS + t0;
  u16* outb = (u16*)out + (long)b * L_SZ * DIN + (long)c * CH * DIN + d0;

  for (int g = 0; g < CH / 8; ++g) {
    union { uint4 v; u16 a[8]; } dt8[4], u8[4];
    union { float4 v[2]; float a[8]; } B8, C8;
#pragma unroll
    for (int dd = 0; dd < 4; ++dd) {
      dt8[dd].v = *(const uint4*)(pdt + (long)dd * MROWS + g * 8);
      u8[dd].v = *(const uint4*)(pu + (long)dd * MROWS + g * 8);
    }
    B8.v[0] = *(const float4*)(pB + g * 8);
    B8.v[1] = *(const float4*)(pB + g * 8 + 4);
    C8.v[0] = *(const float4*)(pC + g * 8);
    C8.v[1] = *(const float4*)(pC + g * 8 + 4);
    u16* og = outb + (long)g * 8 * DIN;
#pragma unroll
    for (int j = 0; j < 8; ++j) {
      float Bj = B8.a[j];
      float Cj = C8.a[j];
      u16 o4[4];
#pragma unroll
      for (int dd = 0; dd < 4; ++dd) {
        float dtv = b2f(dt8[dd].a[j]);
        float uv = b2f(u8[dd].a[j]);
        float da = fexp2(dtv * A2[dd]);
        h[dd] = da * h[dd] + (dtv * uv) * Bj;
        float q = row16_sum(h[dd] * Cj);
        o4[dd] = f2b(q + Dd[dd] * uv);
      }
      if (s == 0) *(uint2*)(og + (long)j * DIN) = *(uint2*)o4;
    }
  }
}

// ---------------------------------------------------------------------------
// LayerNorm over last dim (512). fp32 in; fp32 out + optional bf16 copy.
// ---------------------------------------------------------------------------
__global__ __launch_bounds__(256) void ln_k(
    const float* __restrict__ xin, const float* __restrict__ g,
    const float* __restrict__ bb, float* __restrict__ out,
    bf16* __restrict__ outb) {
  int row = blockIdx.x;
  const float* p = xin + (long)row * DM;
  int tid = threadIdx.x;
  float x0 = p[tid], x1 = p[tid + 256];
  float sum = x0 + x1;
  float sq = x0 * x0 + x1 * x1;
#pragma unroll
  for (int o = 1; o < 64; o <<= 1) {
    sum += __shfl_xor(sum, o, 64);
    sq += __shfl_xor(sq, o, 64);
  }
  __shared__ float ssum[4], ssq[4];
  int wv = tid >> 6;
  if ((tid & 63) == 0) { ssum[wv] = sum; ssq[wv] = sq; }
  __syncthreads();
  sum = ssum[0] + ssum[1] + ssum[2] + ssum[3];
  sq = ssq[0] + ssq[1] + ssq[2] + ssq[3];
  float mean = sum * (1.f / DM);
  float var = sq * (1.f / DM) - mean * mean;
  float rstd = rsqrtf(var + 1e-5f);
  float v0 = (x0 - mean) * rstd * g[tid] + bb[tid];
  float v1 = (x1 - mean) * rstd * g[tid + 256] + bb[tid + 256];
  out[(long)row * DM + tid] = v0;
  out[(long)row * DM + tid + 256] = v1;
  if (outb) {
    stf(outb, (long)row * DM + tid, v0);
    stf(outb, (long)row * DM + tid + 256, v1);
  }
}

// ---------------------------------------------------------------------------
// Orchestration. Workspace: 6 slots x 16 MB = 96 MB:
//  A[0,16):  xs1 -> y1 -> gated y1 -> outacc(fp32)
//  B[16,32): xcT1 (=uT1, live thru scan) -> xln fp32
//  C[32,48): dtT1 (live thru scan) -> newx fp32 -> ffn head (32 MB span C+D)
//  D[48,64): xs2 -> y2 -> gated y2 -> ffn tail
//  E[64,80): xcT2 (=uT2) -> xln bf16
//  F[80,96): dtT2
// d_out (16 MB):
//  Wxs@0 (2MB), Wg@2MB (2MB), o1b@4MB, o2b@5MB, c1b@6MB, c2b@8MB,
//  xdT1@10MB, xdT2@12MB (zeroed via memsetAsync; atomic split-K accum),
//  scan scratch @14MB. All dead before FFN-down; LN2 overwrites d_out.
// ---------------------------------------------------------------------------
extern "C" void kernel_launch(void* const* d_in, const int* in_sizes, int n_in,
                              void* d_out, int out_size, void* d_ws, size_t ws_size,
                              hipStream_t stream) {
  const float* x = (const float*)d_in[0];
  const float* in1_w = (const float*)d_in[1];
  const float* conv1_w = (const float*)d_in[2];
  const float* conv1_b = (const float*)d_in[3];
  const float* xp1_w = (const float*)d_in[4];
  const float* dtp1_w = (const float*)d_in[5];
  const float* dtp1_b = (const float*)d_in[6];
  const float* Alog1 = (const float*)d_in[7];
  const float* D1 = (const float*)d_in[8];
  const float* outp1_w = (const float*)d_in[9];
  const float* in2_w = (const float*)d_in[10];
  const float* conv2_w = (const float*)d_in[11];
  const float* conv2_b = (const float*)d_in[12];
  const float* xp2_w = (const float*)d_in[13];
  const float* dtp2_w = (const float*)d_in[14];
  const float* dtp2_b = (const float*)d_in[15];
  const float* Alog2 = (const float*)d_in[16];
  const float* D2 = (const float*)d_in[17];
  const float* outp2_w = (const float*)d_in[18];
  const float* c1_w = (const float*)d_in[19];
  const float* c1_b = (const float*)d_in[20];
  const float* c2_w = (const float*)d_in[21];
  const float* c2_b = (const float*)d_in[22];
  const float* ln1_g = (const float*)d_in[23];
  const float* ln1_b = (const float*)d_in[24];
  const float* ln2_g = (const float*)d_in[25];
  const float* ln2_b = (const float*)d_in[26];

  const long MB = 1024L * 1024;
  char* wsb = (char*)d_ws;
  bf16* A = (bf16*)(wsb + 0 * MB);
  bf16* B = (bf16*)(wsb + 16 * MB);
  bf16* C = (bf16*)(wsb + 32 * MB);
  bf16* D = (bf16*)(wsb + 48 * MB);
  bf16* E = (bf16*)(wsb + 64 * MB);
  bf16* F = (bf16*)(wsb + 80 * MB);
  float* Bf = (float*)B;   // xln fp32
  float* Cf = (float*)C;   // newx fp32
  float* Af = (float*)A;   // outacc fp32
  bf16* ffn = C;           // 32 MB span C+D, ldc = 2048

  char* ob = (char*)d_out;
  bf16* Wxs = (bf16*)(ob + 0 * MB);    // 2048x512 = 2 MB
  bf16* Wg = (bf16*)(ob + 2 * MB);     // 2048x512 = 2 MB
  bf16* o1b = (bf16*)(ob + 4 * MB);    // 512K (1 MB)
  bf16* o2b = (bf16*)(ob + 5 * MB);
  bf16* c1b = (bf16*)(ob + 6 * MB);    // 1M (2 MB)
  bf16* c2b = (bf16*)(ob + 8 * MB);
  float* xdT1 = (float*)(ob + 10 * MB);  // 64x8192 fp32 (2 MB)
  float* xdT2 = (float*)(ob + 12 * MB);
  float* sd1 = (float*)(ob + 14 * MB);             // 96 KB
  float* sd2 = (float*)(ob + 14 * MB + 131072);    // 96 KB
  bf16* hl1 = (bf16*)(ob + 14 * MB + 262144);      // 768 KB
  bf16* hl2 = (bf16*)(ob + 15 * MB);               // 768 KB

  const long HWN = (long)DIN * DM;   // 524288: one direction's xs (or gate) W

  dim3 blk(256);
  dim3 gP2(2 * DIN / 128, MROWS / 128); // N=2048 merged xs / gate MFMA
  dim3 gM(DM / 128, MROWS / 128);       // N=512 MFMA
  dim3 gF(DFF / 128, MROWS / 128);      // N=2048 MFMA
  dim3 gC(DIN / 64, MROWS / 64);        // convT tiles
  dim3 gXs(MROWS / BN, DIN / 128, 2);   // split-K xproj: 2048 blocks
  dim3 gD(MROWS / BN, DIN / BM);        // dtT: M=1024

  // ---- consolidated weight conversion (1 dispatch) + xdT zero-init ----
  cvt8_k<<<20480, blk, 0, stream>>>(
      in1_w, in2_w, in1_w + HWN, in2_w + HWN, outp1_w, outp2_w, c1_w, c2_w,
      Wxs, Wxs + HWN, Wg, Wg + HWN, o1b, o2b, c1b, c2b);
  hipMemsetAsync(xdT1, 0, 4 * MB, stream);   // xdT1 + xdT2 contiguous

  // ---- merged xs projection: xs1 -> A, xs2 (row-flipped) -> D ----
  mgemm_k<MEPI_STORE2, float, bf16><<<gP2, blk, 0, stream>>>(
      x, DM, Wxs, DM, A, D, DIN, nullptr, nullptr, DM);

  // ---- conv + transpose per direction ----
  convT_k<<<gC, blk, 0, stream>>>(A, conv1_w, conv1_b, B);               // xcT1
  convT_k<<<gC, blk, 0, stream>>>(D, conv2_w, conv2_b, E);               // xcT2

  // ---- x-proj (split-K, both dirs, 1 dispatch) ----
  xprojs_k<<<gXs, blk, 0, stream>>>(xp1_w, B, xdT1, xp2_w, E, xdT2);

  // ---- dt-proj per direction ----
  gemmBT_k<EPI_SOFTPLUS_ROW, float, bf16><<<gD, blk, 0, stream>>>(
      dtp1_w, xdT1, C, MROWS, dtp1_b, DTRANK);                           // dtT1
  gemmBT_k<EPI_SOFTPLUS_ROW, float, bf16><<<gD, blk, 0, stream>>>(
      dtp2_w, xdT2, F, MROWS, dtp2_b, DTRANK);                           // dtT2

  // ---- chunked bidirectional scan (4 d per thread) ----
  scan1_k<<<2 * 8 * 3 * 16, blk, 0, stream>>>(
      (const u16*)C, (const u16*)F, (const u16*)B, (const u16*)E,
      xdT1, xdT2, Alog1, Alog2, hl1, hl2, sd1, sd2);
  scan2_k<<<2 * 8 * 4 * 16, blk, 0, stream>>>(
      (const u16*)C, (const u16*)F, (const u16*)B, (const u16*)E,
      xdT1, xdT2, Alog1, Alog2, D1, D2, hl1, hl2, sd1, sd2, A, D);

  // ---- merged gates (in-place over y1 in A, y2 in D) ----
  mgemm_k<MEPI_GATE2, float, bf16><<<gP2, blk, 0, stream>>>(
      x, DM, Wg, DM, A, D, DIN, nullptr, nullptr, DM);

  // ---- merge: newx = y1@W1^T + flip(y2)@W2^T + x -> C (fp32) ----
  mmerge_k<<<gM, blk, 0, stream>>>(A, D, o1b, o2b, x, Cf);

  // ---- LN1: fp32 -> B, bf16 -> E ----
  ln_k<<<MROWS, blk, 0, stream>>>(Cf, ln1_g, ln1_b, Bf, E);

  // ---- FFN (single up, single down) ----
  mgemm_k<MEPI_BIAS_GELU, bf16, bf16><<<gF, blk, 0, stream>>>(
      E, DM, c1b, DM, ffn, nullptr, DFF, c1_b, nullptr, DM);
  mgemm_k<MEPI_BIAS_RES, bf16, float><<<gM, blk, 0, stream>>>(
      ffn, DFF, c2b, DFF, Af, nullptr, DM, c2_b, Bf, DFF);

  // ---- LN2 -> d_out (all d_out scratch dead) ----
  ln_k<<<MROWS, blk, 0, stream>>>(Af, ln2_g, ln2_b, (float*)d_out, nullptr);
}

// Round 11
// 726.474 us; speedup vs baseline: 1.2135x; 1.2135x over previous
//
#include <hip/hip_runtime.h>
#include <hip/hip_bf16.h>
#include <math.h>

// ---------------------------------------------------------------------------
// Problem constants
// ---------------------------------------------------------------------------
#define B_SZ 8
#define L_SZ 1024
#define DM 512          // d_model
#define DFF 2048        // d_ff
#define DIN 1024        // expand * d_model
#define DSTATE 16
#define DTRANK 32
#define MROWS (B_SZ * L_SZ)   // 8192
#define CH 256                // scan chunk length
#define NCH 4                 // chunks per sequence

typedef __hip_bfloat16 bf16;
typedef unsigned short u16;
using f32x4 = __attribute__((ext_vector_type(4))) float;
using bfrag = __attribute__((ext_vector_type(8))) short;   // 8 bf16 = 4 VGPR

__device__ inline float ldf(const float* p, long i) { return p[i]; }
__device__ inline float ldf(const bf16* p, long i) {
  return __uint_as_float((unsigned)((const u16*)p)[i] << 16);
}
__device__ inline void stf(float* p, long i, float v) { p[i] = v; }
__device__ inline void stf(bf16* p, long i, float v) { p[i] = __float2bfloat16(v); }
__device__ inline float b2f(u16 x) {
  return __uint_as_float((unsigned)x << 16);
}
__device__ inline u16 f2b(float v) {
  union { bf16 h; u16 u; } c;
  c.h = __float2bfloat16(v);
  return c.u;
}

// Raw v_exp_f32: computes 2^x in one trans-pipe instruction.
__device__ inline float fexp2(float x) {
  float r;
  asm("v_exp_f32 %0, %1" : "=v"(r) : "v"(x));
  return r;
}

// Async global->LDS, 16B per lane. LDS dest is wave-uniform base + lane*16;
// global source is per-lane. Compiler emits vmcnt(0) before s_barrier, so
// __syncthreads() after issuing guarantees completion (m97 pattern).
typedef __attribute__((address_space(1))) const void g_void;
typedef __attribute__((address_space(3))) void l_void;
__device__ inline void gl_lds16(const void* g, void* l) {
  __builtin_amdgcn_global_load_lds((g_void*)g, (l_void*)l, 16, 0, 0);
}

// B-element loader (4 consecutive): fp32 direct, bf16 convert.
__device__ inline float4 ld4f_bt(const float* p) { return *(const float4*)p; }
__device__ inline float4 ld4f_bt(const bf16* p) {
  ushort4 u = *(const ushort4*)p;
  float4 v;
  v.x = b2f(u.x); v.y = b2f(u.y); v.z = b2f(u.z); v.w = b2f(u.w);
  return v;
}

// 16-element row loader into packed bf16 (2 x uint4), fp32 src (RNE convert).
__device__ inline void ld16f(const float* p, uint4& lo, uint4& hi) {
  float4 a = *(const float4*)p, b = *(const float4*)(p + 4);
  float4 c = *(const float4*)(p + 8), d = *(const float4*)(p + 12);
  union { uint4 v; u16 s[8]; } L, H;
  L.s[0] = f2b(a.x); L.s[1] = f2b(a.y); L.s[2] = f2b(a.z); L.s[3] = f2b(a.w);
  L.s[4] = f2b(b.x); L.s[5] = f2b(b.y); L.s[6] = f2b(b.z); L.s[7] = f2b(b.w);
  H.s[0] = f2b(c.x); H.s[1] = f2b(c.y); H.s[2] = f2b(c.z); H.s[3] = f2b(c.w);
  H.s[4] = f2b(d.x); H.s[5] = f2b(d.y); H.s[6] = f2b(d.z); H.s[7] = f2b(d.w);
  lo = L.v; hi = H.v;
}

// Fused DPP rotate-add reduce within 16-lane row.
__device__ inline float dpp_add_r8(float x) {
  float r; asm("v_add_f32 %0, %1, %2 row_ror:8" : "=v"(r) : "v"(x), "v"(x)); return r;
}
__device__ inline float dpp_add_r4(float x) {
  float r; asm("v_add_f32 %0, %1, %2 row_ror:4" : "=v"(r) : "v"(x), "v"(x)); return r;
}
__device__ inline float dpp_add_r2(float x) {
  float r; asm("v_add_f32 %0, %1, %2 row_ror:2" : "=v"(r) : "v"(x), "v"(x)); return r;
}
__device__ inline float dpp_add_r1(float x) {
  float r; asm("v_add_f32 %0, %1, %2 row_ror:1" : "=v"(r) : "v"(x), "v"(x)); return r;
}
__device__ inline float row16_sum(float x) {
  return dpp_add_r1(dpp_add_r2(dpp_add_r4(dpp_add_r8(x))));
}

__device__ inline int flipL(int r) {
  int t = r & (L_SZ - 1);
  return (r - t) + (L_SZ - 1 - t);
}

// ---------------------------------------------------------------------------
// Consolidated fp32 -> bf16 weight conversion: 8 segments, one dispatch.
// ---------------------------------------------------------------------------
__global__ __launch_bounds__(256) void cvt8_k(
    const float* s0, const float* s1, const float* s2, const float* s3,
    const float* s4, const float* s5, const float* s6, const float* s7,
    bf16* d0, bf16* d1, bf16* d2, bf16* d3,
    bf16* d4, bf16* d5, bf16* d6, bf16* d7) {
  int blk = blockIdx.x;
  const float* s; bf16* d; long off;
  if (blk < 2048)       { s = s0; d = d0; off = (long)blk * 256; }
  else if (blk < 4096)  { s = s1; d = d1; off = (long)(blk - 2048) * 256; }
  else if (blk < 6144)  { s = s2; d = d2; off = (long)(blk - 4096) * 256; }
  else if (blk < 8192)  { s = s3; d = d3; off = (long)(blk - 6144) * 256; }
  else if (blk < 10240) { s = s4; d = d4; off = (long)(blk - 8192) * 256; }
  else if (blk < 12288) { s = s5; d = d5; off = (long)(blk - 10240) * 256; }
  else if (blk < 16384) { s = s6; d = d6; off = (long)(blk - 12288) * 256; }
  else                  { s = s7; d = d7; off = (long)(blk - 16384) * 256; }
  off += threadIdx.x;
  d[off] = __float2bfloat16(s[off]);
}

// ---------------------------------------------------------------------------
// bf16 MFMA GEMM: C(M,N) = A(M,K) @ W(N,K)^T, fp32 accumulate.
// 128x128 tile, BK=32, 4 waves, each 64x64 via 4x4 v_mfma_f32_16x16x32_bf16.
// W staged via global_load_lds width=16. A: bf16 -> gload_lds; fp32 ->
// inline-convert register path. LDS sized per-path via constexpr.
// Merged epilogues: STORE2 / GATE2 route cols >= DIN to C2[flipL(row)].
// ---------------------------------------------------------------------------
constexpr int MEPI_STORE2 = 0;
constexpr int MEPI_GATE2 = 1;
constexpr int MEPI_BIAS_GELU = 2;   // bf16 out
constexpr int MEPI_BIAS_RES = 3;    // fp32 out = acc + bias + res

template <int EPI, typename TA, typename TO>
__global__ __launch_bounds__(256) void mgemm_k(
    const TA* __restrict__ Ab, int lda,
    const bf16* __restrict__ Wb, int ldw,
    TO* __restrict__ C, TO* __restrict__ C2, int ldc,
    const float* __restrict__ bias,
    const float* __restrict__ res,
    int K) {
  constexpr bool ABF = (sizeof(TA) == 2);   // bf16 A -> gload_lds path
  __shared__ u16 Wsm[128][32];
  __shared__ u16 AsmL[ABF ? 128 : 1][32];
  __shared__ u16 AsmP[ABF ? 1 : 128][ABF ? 1 : 40];
  const int tid = threadIdx.x;
  const int m0 = blockIdx.y * 128;
  const int n0 = blockIdx.x * 128;

  const int srow4 = tid >> 2;          // 0..63
  const int q16 = tid & 3;             // 16B chunk in row
  const u16* Wg0 = (const u16*)Wb + (long)(n0 + srow4) * ldw + q16 * 8;
  const u16* Wg1 = (const u16*)Wb + (long)(n0 + 64 + srow4) * ldw + q16 * 8;
  char* WsmB = (char*)&Wsm[0][0] + (tid >> 6) * 1024;   // wave-uniform

  const u16* Ag0 = (const u16*)Ab + (long)(m0 + srow4) * lda + q16 * 8;
  const u16* Ag1 = (const u16*)Ab + (long)(m0 + 64 + srow4) * lda + q16 * 8;
  char* AsmB = (char*)&AsmL[0][0] + (tid >> 6) * 1024;

  const int srow = tid >> 1;
  const int scol = (tid & 1) * 16;
  const TA* Agf = Ab + (long)(m0 + srow) * lda + scol;

  const int lane = tid & 63, quad = lane >> 4, l16 = lane & 15;
  const int wid = tid >> 6;
  const int wm = (wid & 1) * 64, wn = (wid >> 1) * 64;

  f32x4 acc[4][4];
#pragma unroll
  for (int i = 0; i < 4; ++i)
#pragma unroll
    for (int j = 0; j < 4; ++j) acc[i][j] = {0.f, 0.f, 0.f, 0.f};

  for (int k0 = 0; k0 < K; k0 += 32) {
    uint4 av0, av1;
    if constexpr (!ABF) ld16f((const float*)(Agf + k0), av0, av1);
    __syncthreads();   // previous iteration's frag reads complete
    gl_lds16(Wg0 + k0, WsmB);
    gl_lds16(Wg1 + k0, WsmB + 4096);
    if constexpr (ABF) {
      gl_lds16(Ag0 + k0, AsmB);
      gl_lds16(Ag1 + k0, AsmB + 4096);
    } else {
      *(uint4*)&AsmP[srow][scol] = av0;
      *(uint4*)&AsmP[srow][scol + 8] = av1;
    }
    __syncthreads();   // vmcnt(0)+lgkmcnt(0) drained before barrier
    bfrag a[4], b[4];
#pragma unroll
    for (int mi = 0; mi < 4; ++mi) {
      if constexpr (ABF)
        a[mi] = *(const bfrag*)&AsmL[wm + mi * 16 + l16][quad * 8];
      else
        a[mi] = *(const bfrag*)&AsmP[wm + mi * 16 + l16][quad * 8];
    }
#pragma unroll
    for (int ni = 0; ni < 4; ++ni)
      b[ni] = *(const bfrag*)&Wsm[wn + ni * 16 + l16][quad * 8];
#pragma unroll
    for (int mi = 0; mi < 4; ++mi)
#pragma unroll
      for (int ni = 0; ni < 4; ++ni)
        acc[mi][ni] = __builtin_amdgcn_mfma_f32_16x16x32_bf16(
            a[mi], b[ni], acc[mi][ni], 0, 0, 0);
  }

  const bool second = (n0 >= DIN);   // block-uniform (128 | DIN)
#pragma unroll
  for (int mi = 0; mi < 4; ++mi)
#pragma unroll
    for (int ni = 0; ni < 4; ++ni)
#pragma unroll
      for (int r = 0; r < 4; ++r) {
        int row = m0 + wm + mi * 16 + quad * 4 + r;
        int col = n0 + wn + ni * 16 + l16;
        float v = acc[mi][ni][r];
        if (EPI == MEPI_STORE2) {
          if (second) stf(C2, (long)flipL(row) * ldc + (col - DIN), v);
          else stf(C, (long)row * ldc + col, v);
        } else if (EPI == MEPI_GATE2) {
          TO* T = second ? C2 : C;
          long oi = second ? ((long)flipL(row) * ldc + (col - DIN))
                           : ((long)row * ldc + col);
          float y = ldf((const bf16*)T, oi);
          float sz = v / (1.f + __expf(-v));
          stf(T, oi, y * sz);
        } else if (EPI == MEPI_BIAS_GELU) {
          long oi = (long)row * ldc + col;
          v += bias[col];
          v = 0.5f * v * (1.f + erff(v * 0.70710678118654752440f));
          stf(C, oi, v);
        } else if (EPI == MEPI_BIAS_RES) {
          long oi = (long)row * ldc + col;
          ((float*)C)[oi] = v + bias[col] + res[oi];
        }
      }
}

// ---------------------------------------------------------------------------
// MFMA merge: newx(M,DM) = y1 @ W1^T + flip_L(y2) @ W2^T + xres (fp32 out).
// ---------------------------------------------------------------------------
__global__ __launch_bounds__(256) void mmerge_k(
    const bf16* __restrict__ y1, const bf16* __restrict__ y2,
    const bf16* __restrict__ W1, const bf16* __restrict__ W2,
    const float* __restrict__ xres, float* __restrict__ newx) {
  __shared__ u16 AsmL[128][32];
  __shared__ u16 Wsm[128][32];
  const int tid = threadIdx.x;
  const int m0 = blockIdx.y * 128;
  const int n0 = blockIdx.x * 128;

  const int srow4 = tid >> 2;
  const int q16 = tid & 3;
  int r1a = m0 + srow4, r1b = m0 + 64 + srow4;
  int r2a = flipL(r1a), r2b = flipL(r1b);
  const u16* A1g0 = (const u16*)y1 + (long)r1a * DIN + q16 * 8;
  const u16* A1g1 = (const u16*)y1 + (long)r1b * DIN + q16 * 8;
  const u16* A2g0 = (const u16*)y2 + (long)r2a * DIN + q16 * 8;
  const u16* A2g1 = (const u16*)y2 + (long)r2b * DIN + q16 * 8;
  const u16* W1g0 = (const u16*)W1 + (long)(n0 + srow4) * DIN + q16 * 8;
  const u16* W1g1 = (const u16*)W1 + (long)(n0 + 64 + srow4) * DIN + q16 * 8;
  const u16* W2g0 = (const u16*)W2 + (long)(n0 + srow4) * DIN + q16 * 8;
  const u16* W2g1 = (const u16*)W2 + (long)(n0 + 64 + srow4) * DIN + q16 * 8;
  char* AsmB = (char*)&AsmL[0][0] + (tid >> 6) * 1024;
  char* WsmB = (char*)&Wsm[0][0] + (tid >> 6) * 1024;

  const int lane = tid & 63, quad = lane >> 4, l16 = lane & 15;
  const int wid = tid >> 6;
  const int wm = (wid & 1) * 64, wn = (wid >> 1) * 64;

  f32x4 acc[4][4];
#pragma unroll
  for (int i = 0; i < 4; ++i)
#pragma unroll
    for (int j = 0; j < 4; ++j) acc[i][j] = {0.f, 0.f, 0.f, 0.f};

  for (int k0 = 0; k0 < 2 * DIN; k0 += 32) {
    const bool ph2 = (k0 >= DIN);
    const int kk = k0 & (DIN - 1);
    const u16* a0 = ph2 ? A2g0 : A1g0;
    const u16* a1 = ph2 ? A2g1 : A1g1;
    const u16* w0 = ph2 ? W2g0 : W1g0;
    const u16* w1 = ph2 ? W2g1 : W1g1;
    __syncthreads();
    gl_lds16(a0 + kk, AsmB);
    gl_lds16(a1 + kk, AsmB + 4096);
    gl_lds16(w0 + kk, WsmB);
    gl_lds16(w1 + kk, WsmB + 4096);
    __syncthreads();
    bfrag a[4], b[4];
#pragma unroll
    for (int mi = 0; mi < 4; ++mi)
      a[mi] = *(const bfrag*)&AsmL[wm + mi * 16 + l16][quad * 8];
#pragma unroll
    for (int ni = 0; ni < 4; ++ni)
      b[ni] = *(const bfrag*)&Wsm[wn + ni * 16 + l16][quad * 8];
#pragma unroll
    for (int mi = 0; mi < 4; ++mi)
#pragma unroll
      for (int ni = 0; ni < 4; ++ni)
        acc[mi][ni] = __builtin_amdgcn_mfma_f32_16x16x32_bf16(
            a[mi], b[ni], acc[mi][ni], 0, 0, 0);
  }

#pragma unroll
  for (int mi = 0; mi < 4; ++mi)
#pragma unroll
    for (int ni = 0; ni < 4; ++ni)
#pragma unroll
      for (int r = 0; r < 4; ++r) {
        int row = m0 + wm + mi * 16 + quad * 4 + r;
        int col = n0 + wn + ni * 16 + l16;
        long oi = (long)row * DM + col;
        newx[oi] = acc[mi][ni][r] + xres[oi];
      }
}

// ---------------------------------------------------------------------------
// Vector-ALU GEMM with ROW-MAJOR B: C(M,N) = A(M,K) @ B(K,N).
// Used only for dtT (K=32, 2048 blocks -> well occupied).
// ---------------------------------------------------------------------------
constexpr int EPI_NONE = 0;
constexpr int EPI_SOFTPLUS_ROW = 1;

#define BM 64
#define BN 64
#define BKK 16

template <int EPI, typename TB, typename TO>
__global__ __launch_bounds__(256) void gemmBT_k(
    const float* __restrict__ A,
    const TB* __restrict__ B,
    TO* __restrict__ C, int N,
    const float* __restrict__ bias, int K) {
  __shared__ float As[BKK][BM + 4];
  __shared__ float Bs[BKK][BN + 4];
  const int tid = threadIdx.x;
  const int m0 = blockIdx.y * BM;
  const int n0 = blockIdx.x * BN;
  const int tx = tid & 15;
  const int ty = tid >> 4;
  const int lrow = tid >> 2;
  const int lcol = (tid & 3) * 4;
  const int kr = tid >> 4;
  const int nc = (tid & 15) * 4;

  const float* Arow = A + (long)(m0 + lrow) * K;

  float acc[4][4] = {};
  for (int k0 = 0; k0 < K; k0 += BKK) {
    float4 av = *(const float4*)(Arow + k0 + lcol);
    float4 bv = ld4f_bt(B + (long)(k0 + kr) * N + n0 + nc);
    As[lcol + 0][lrow] = av.x; As[lcol + 1][lrow] = av.y;
    As[lcol + 2][lrow] = av.z; As[lcol + 3][lrow] = av.w;
    Bs[kr][nc + 0] = bv.x; Bs[kr][nc + 1] = bv.y;
    Bs[kr][nc + 2] = bv.z; Bs[kr][nc + 3] = bv.w;
    __syncthreads();
#pragma unroll
    for (int k = 0; k < BKK; ++k) {
      float a[4], b[4];
#pragma unroll
      for (int i = 0; i < 4; ++i) a[i] = As[k][ty * 4 + i];
#pragma unroll
      for (int j = 0; j < 4; ++j) b[j] = Bs[k][tx * 4 + j];
#pragma unroll
      for (int i = 0; i < 4; ++i)
#pragma unroll
        for (int j = 0; j < 4; ++j) acc[i][j] += a[i] * b[j];
    }
    __syncthreads();
  }

#pragma unroll
  for (int i = 0; i < 4; ++i) {
    int r = m0 + ty * 4 + i;
#pragma unroll
    for (int j = 0; j < 4; ++j) {
      int c = n0 + tx * 4 + j;
      float v = acc[i][j];
      if (EPI == EPI_SOFTPLUS_ROW) {
        v += bias[r];
        v = (v > 20.f) ? v : log1pf(__expf(v));
      }
      stf(C, (long)r * N + c, v);
    }
  }
}

// ---------------------------------------------------------------------------
// R11: split-K x-projection, NO atomics (R10's atomicAdd serialized at the
// coherence point: 8.4M contended device-scope atomics -> regression).
// Each block writes a 64x64 PARTIAL for its K-slice into a private buffer;
// xred_k sums the 4 slices. Partials live in ws slots A and D, which are
// dead during this phase (xs consumed by the preceding convTs; scan2
// rewrites A/D only after xred has consumed the partials; stream-ordered).
// Grid (128 N-tiles, 4 K-slices, 2 dirs) = 1024 blocks = 4/CU, 4 waves/SIMD
// (old xdblT: 128 blocks = 0.5 block/CU, 1 wave/SIMD, exposed LDS latency).
// ---------------------------------------------------------------------------
#define XSLICE 4
#define XSZ ((long)64 * MROWS)   // one partial plane: 2 MB fp32

__global__ __launch_bounds__(256) void xprojs_k(
    const float* __restrict__ A1, const bf16* __restrict__ B1,
    float* __restrict__ P1,
    const float* __restrict__ A2, const bf16* __restrict__ B2,
    float* __restrict__ P2) {
  __shared__ float As[BKK][BM + 4];
  __shared__ float Bs[BKK][BN + 4];
  const int tid = threadIdx.x;
  const int n0 = blockIdx.x * BN;
  const int slice = blockIdx.y;
  const int kbeg = slice * (DIN / XSLICE);
  const int dir = blockIdx.z;
  const float* A = dir ? A2 : A1;
  const bf16* Bm = dir ? B2 : B1;
  float* P = (dir ? P2 : P1) + (long)slice * XSZ;
  const int N = MROWS, K = DIN;
  const int tx = tid & 15;
  const int ty = tid >> 4;
  const int lrow = tid >> 2;        // m index 0..63 (BM=64 covers all M)
  const int lcol = (tid & 3) * 4;
  const int kr = tid >> 4;
  const int nc = (tid & 15) * 4;

  const float* Arow = A + (long)lrow * K;

  float acc[4][4] = {};
  for (int k0 = kbeg; k0 < kbeg + DIN / XSLICE; k0 += BKK) {
    float4 av = *(const float4*)(Arow + k0 + lcol);
    float4 bv = ld4f_bt(Bm + (long)(k0 + kr) * N + n0 + nc);
    As[lcol + 0][lrow] = av.x; As[lcol + 1][lrow] = av.y;
    As[lcol + 2][lrow] = av.z; As[lcol + 3][lrow] = av.w;
    Bs[kr][nc + 0] = bv.x; Bs[kr][nc + 1] = bv.y;
    Bs[kr][nc + 2] = bv.z; Bs[kr][nc + 3] = bv.w;
    __syncthreads();
#pragma unroll
    for (int k = 0; k < BKK; ++k) {
      float a[4], b[4];
#pragma unroll
      for (int i = 0; i < 4; ++i) a[i] = As[k][ty * 4 + i];
#pragma unroll
      for (int j = 0; j < 4; ++j) b[j] = Bs[k][tx * 4 + j];
#pragma unroll
      for (int i = 0; i < 4; ++i)
#pragma unroll
        for (int j = 0; j < 4; ++j) acc[i][j] += a[i] * b[j];
    }
    __syncthreads();
  }

#pragma unroll
  for (int i = 0; i < 4; ++i) {
    int r = ty * 4 + i;
#pragma unroll
    for (int j = 0; j < 4; ++j) {
      int c = n0 + tx * 4 + j;
      P[(long)r * N + c] = acc[i][j];
    }
  }
}

// Reduce 4 K-slice partials -> xdT (fp32). 2048 blocks x 2 dirs; ~20MB traffic.
__global__ __launch_bounds__(256) void xred_k(
    const float* __restrict__ P1, float* __restrict__ o1,
    const float* __restrict__ P2, float* __restrict__ o2) {
  long i = (long)blockIdx.x * 256 + threadIdx.x;   // 0 .. XSZ-1
  const float* P = blockIdx.y ? P2 : P1;
  float* o = blockIdx.y ? o2 : o1;
  o[i] = P[i] + P[i + XSZ] + P[i + 2 * XSZ] + P[i + 3 * XSZ];
}

// ---------------------------------------------------------------------------
// Fused depthwise causal conv (k=4) + bias + silu + TRANSPOSE.
// ---------------------------------------------------------------------------
__global__ __launch_bounds__(256) void convT_k(
    const bf16* __restrict__ xs, const float* __restrict__ w,
    const float* __restrict__ b, bf16* __restrict__ xcT) {
  __shared__ u16 T[64][72];
  int c0 = blockIdx.x * 64;
  int r0 = blockIdx.y * 64;
  int tid = threadIdx.x;
  int tr = tid >> 2;
  int tc = (tid & 3) * 16;

  const u16* src = (const u16*)xs + (long)(r0 + tr) * DIN + c0 + tc;
  uint4 v0 = *(const uint4*)src;
  uint4 v1 = *(const uint4*)(src + 8);
  u16 tmp[16];
  *(uint4*)tmp = v0;
  *(uint4*)(tmp + 8) = v1;
#pragma unroll
  for (int j = 0; j < 16; ++j) T[tc + j][tr + 3] = tmp[j];
  bool head = (r0 & (L_SZ - 1)) == 0;
  if (tid < 12) {
    int hr = tid >> 2;
    int seg = (tid & 3) * 16;
    if (head) {
#pragma unroll
      for (int j = 0; j < 16; ++j) T[seg + j][hr] = 0;
    } else {
      const u16* hs = (const u16*)xs + (long)(r0 - 3 + hr) * DIN + c0 + seg;
      uint4 h0 = *(const uint4*)hs;
      uint4 h1 = *(const uint4*)(hs + 8);
      u16 ht[16];
      *(uint4*)ht = h0;
      *(uint4*)(ht + 8) = h1;
#pragma unroll
      for (int j = 0; j < 16; ++j) T[seg + j][hr] = ht[j];
    }
  }
  __syncthreads();

  int d = c0 + tr;
  float w0 = w[d * 4 + 0], w1 = w[d * 4 + 1], w2 = w[d * 4 + 2], w3 = w[d * 4 + 3];
  float bd = b[d];
  float X[19];
#pragma unroll
  for (int k = 0; k < 19; ++k) X[k] = b2f(T[tr][tc + k]);
  u16 o[16];
#pragma unroll
  for (int j = 0; j < 16; ++j) {
    float acc = bd + w0 * X[j] + w1 * X[j + 1] + w2 * X[j + 2] + w3 * X[j + 3];
    o[j] = f2b(acc / (1.f + __expf(-acc)));
  }
  u16* dst = (u16*)xcT + (long)d * MROWS + r0 + tc;
  *(uint4*)dst = *(uint4*)o;
  *(uint4*)(dst + 8) = *(uint4*)(o + 8);
}

// ---------------------------------------------------------------------------
// Chunked bidirectional selective scan, 4 d-channels per thread (R7, proven:
// 306 -> 136us; per-CU request-rate was the limit, B/C loads shared over 4 d).
// ---------------------------------------------------------------------------
__global__ __launch_bounds__(256, 4) void scan1_k(
    const u16* __restrict__ dtT1, const u16* __restrict__ dtT2,
    const u16* __restrict__ uT1, const u16* __restrict__ uT2,
    const float* __restrict__ xd1, const float* __restrict__ xd2,
    const float* __restrict__ Alog1, const float* __restrict__ Alog2,
    bf16* __restrict__ hl1, bf16* __restrict__ hl2,
    float* __restrict__ sd1, float* __restrict__ sd2) {
  int blk = blockIdx.x;
  int dblk = blk & 15;
  int r = blk >> 4;
  int c = r % 3; r /= 3;
  int b = r & 7;
  int dir = r >> 3;
  int tid = threadIdx.x;
  int s = tid & 15;
  int gi = tid >> 4;
  int d0 = dblk * 64 + gi * 4;
  const u16* dtT = dir ? dtT2 : dtT1;
  const u16* uT = dir ? uT2 : uT1;
  const float* xd = dir ? xd2 : xd1;
  const float* Alog = dir ? Alog2 : Alog1;
  bf16* hl = dir ? hl2 : hl1;
  float* sd = dir ? sd2 : sd1;

  float A2[4], h[4], sdt[4];
#pragma unroll
  for (int dd = 0; dd < 4; ++dd) {
    A2[dd] = -__expf(Alog[(d0 + dd) * DSTATE + s]) * 1.4426950408889634f;
    h[dd] = 0.f;
    sdt[dd] = 0.f;
  }
  long t0 = (long)b * L_SZ + c * CH;
  const u16* pdt = dtT + (long)d0 * MROWS + t0;
  const u16* pu = uT + (long)d0 * MROWS + t0;
  const float* pB = xd + (long)(DTRANK + s) * MROWS + t0;

  for (int g = 0; g < CH / 8; ++g) {
    union { uint4 v; u16 a[8]; } dt8[4], u8[4];
    union { float4 v[2]; float a[8]; } B8;
#pragma unroll
    for (int dd = 0; dd < 4; ++dd) {
      dt8[dd].v = *(const uint4*)(pdt + (long)dd * MROWS + g * 8);
      u8[dd].v = *(const uint4*)(pu + (long)dd * MROWS + g * 8);
    }
    B8.v[0] = *(const float4*)(pB + g * 8);
    B8.v[1] = *(const float4*)(pB + g * 8 + 4);
#pragma unroll
    for (int j = 0; j < 8; ++j) {
      float Bj = B8.a[j];
#pragma unroll
      for (int dd = 0; dd < 4; ++dd) {
        float dtv = b2f(dt8[dd].a[j]);
        float uv = b2f(u8[dd].a[j]);
        float da = fexp2(dtv * A2[dd]);
        h[dd] = da * h[dd] + (dtv * uv) * Bj;
        sdt[dd] += dtv;
      }
    }
  }
#pragma unroll
  for (int dd = 0; dd < 4; ++dd) {
    int ci = (b * 3 + c) * 1024 + d0 + dd;
    hl[(long)ci * 16 + s] = __float2bfloat16(h[dd]);
    if (s == 0) sd[ci] = sdt[dd];
  }
}

__global__ __launch_bounds__(256, 4) void scan2_k(
    const u16* __restrict__ dtT1, const u16* __restrict__ dtT2,
    const u16* __restrict__ uT1, const u16* __restrict__ uT2,
    const float* __restrict__ xd1, const float* __restrict__ xd2,
    const float* __restrict__ Alog1, const float* __restrict__ Alog2,
    const float* __restrict__ D1, const float* __restrict__ D2,
    const bf16* __restrict__ hl1, const bf16* __restrict__ hl2,
    const float* __restrict__ sd1, const float* __restrict__ sd2,
    bf16* __restrict__ y1, bf16* __restrict__ y2) {
  int blk = blockIdx.x;
  int dblk = blk & 15;
  int c = (blk >> 4) & 3;
  int b = (blk >> 6) & 7;
  int dir = blk >> 9;
  int tid = threadIdx.x;
  int s = tid & 15;
  int gi = tid >> 4;
  int d0 = dblk * 64 + gi * 4;
  const u16* dtT = dir ? dtT2 : dtT1;
  const u16* uT = dir ? uT2 : uT1;
  const float* xd = dir ? xd2 : xd1;
  const float* Alog = dir ? Alog2 : Alog1;
  const float* Dp = dir ? D2 : D1;
  const bf16* hl = dir ? hl2 : hl1;
  const float* sd = dir ? sd2 : sd1;
  bf16* out = dir ? y2 : y1;

  float A2[4], h[4], Dd[4];
#pragma unroll
  for (int dd = 0; dd < 4; ++dd) {
    A2[dd] = -__expf(Alog[(d0 + dd) * DSTATE + s]) * 1.4426950408889634f;
    Dd[dd] = Dp[d0 + dd];
    h[dd] = 0.f;
  }

  for (int cc = 0; cc < c; ++cc) {
#pragma unroll
    for (int dd = 0; dd < 4; ++dd) {
      int ci = (b * 3 + cc) * 1024 + d0 + dd;
      float P = fexp2(A2[dd] * sd[ci]);
      h[dd] = h[dd] * P + b2f(((const u16*)hl)[(long)ci * 16 + s]);
    }
  }

  long t0 = (long)b * L_SZ + c * CH;
  const u16* pdt = dtT + (long)d0 * MROWS + t0;
  const u16* pu = uT + (long)d0 * MROWS + t0;
  const float* pB = xd + (long)(DTRANK + s) * MROWS + t0;
  const float* pC = xd + (long)(DTRANK + DSTATE + s) * MROWS + t0;
  u16* outb = (u16*)out + (long)b * L_SZ * DIN + (long)c * CH * DIN + d0;

  for (int g = 0; g < CH / 8; ++g) {
    union { uint4 v; u16 a[8]; } dt8[4], u8[4];
    union { float4 v[2]; float a[8]; } B8, C8;
#pragma unroll
    for (int dd = 0; dd < 4; ++dd) {
      dt8[dd].v = *(const uint4*)(pdt + (long)dd * MROWS + g * 8);
      u8[dd].v = *(const uint4*)(pu + (long)dd * MROWS + g * 8);
    }
    B8.v[0] = *(const float4*)(pB + g * 8);
    B8.v[1] = *(const float4*)(pB + g * 8 + 4);
    C8.v[0] = *(const float4*)(pC + g * 8);
    C8.v[1] = *(const float4*)(pC + g * 8 + 4);
    u16* og = outb + (long)g * 8 * DIN;
#pragma unroll
    for (int j = 0; j < 8; ++j) {
      float Bj = B8.a[j];
      float Cj = C8.a[j];
      u16 o4[4];
#pragma unroll
      for (int dd = 0; dd < 4; ++dd) {
        float dtv = b2f(dt8[dd].a[j]);
        float uv = b2f(u8[dd].a[j]);
        float da = fexp2(dtv * A2[dd]);
        h[dd] = da * h[dd] + (dtv * uv) * Bj;
        float q = row16_sum(h[dd] * Cj);
        o4[dd] = f2b(q + Dd[dd] * uv);
      }
      if (s == 0) *(uint2*)(og + (long)j * DIN) = *(uint2*)o4;
    }
  }
}

// ---------------------------------------------------------------------------
// LayerNorm over last dim (512). fp32 in; fp32 out + optional bf16 copy.
// ---------------------------------------------------------------------------
__global__ __launch_bounds__(256) void ln_k(
    const float* __restrict__ xin, const float* __restrict__ g,
    const float* __restrict__ bb, float* __restrict__ out,
    bf16* __restrict__ outb) {
  int row = blockIdx.x;
  const float* p = xin + (long)row * DM;
  int tid = threadIdx.x;
  float x0 = p[tid], x1 = p[tid + 256];
  float sum = x0 + x1;
  float sq = x0 * x0 + x1 * x1;
#pragma unroll
  for (int o = 1; o < 64; o <<= 1) {
    sum += __shfl_xor(sum, o, 64);
    sq += __shfl_xor(sq, o, 64);
  }
  __shared__ float ssum[4], ssq[4];
  int wv = tid >> 6;
  if ((tid & 63) == 0) { ssum[wv] = sum; ssq[wv] = sq; }
  __syncthreads();
  sum = ssum[0] + ssum[1] + ssum[2] + ssum[3];
  sq = ssq[0] + ssq[1] + ssq[2] + ssq[3];
  float mean = sum * (1.f / DM);
  float var = sq * (1.f / DM) - mean * mean;
  float rstd = rsqrtf(var + 1e-5f);
  float v0 = (x0 - mean) * rstd * g[tid] + bb[tid];
  float v1 = (x1 - mean) * rstd * g[tid + 256] + bb[tid + 256];
  out[(long)row * DM + tid] = v0;
  out[(long)row * DM + tid + 256] = v1;
  if (outb) {
    stf(outb, (long)row * DM + tid, v0);
    stf(outb, (long)row * DM + tid + 256, v1);
  }
}

// ---------------------------------------------------------------------------
// Orchestration. Workspace: 6 slots x 16 MB = 96 MB:
//  A[0,16):  xs1 -> xproj partials P1 (8MB) -> y1 -> gated y1 -> outacc(fp32)
//  B[16,32): xcT1 (=uT1, live thru scan) -> xln fp32
//  C[32,48): dtT1 (live thru scan) -> newx fp32 -> ffn head (32 MB span C+D)
//  D[48,64): xs2 -> xproj partials P2 (8MB) -> y2 -> gated y2 -> ffn tail
//  E[64,80): xcT2 (=uT2) -> xln bf16
//  F[80,96): dtT2
// d_out (16 MB):
//  Wxs@0 (2MB), Wg@2MB (2MB), o1b@4MB, o2b@5MB, c1b@6MB, c2b@8MB,
//  xdT1@10MB, xdT2@12MB (written by xred), scan scratch @14MB.
//  All dead before FFN-down; LN2 overwrites d_out at the end.
// ---------------------------------------------------------------------------
extern "C" void kernel_launch(void* const* d_in, const int* in_sizes, int n_in,
                              void* d_out, int out_size, void* d_ws, size_t ws_size,
                              hipStream_t stream) {
  const float* x = (const float*)d_in[0];
  const float* in1_w = (const float*)d_in[1];
  const float* conv1_w = (const float*)d_in[2];
  const float* conv1_b = (const float*)d_in[3];
  const float* xp1_w = (const float*)d_in[4];
  const float* dtp1_w = (const float*)d_in[5];
  const float* dtp1_b = (const float*)d_in[6];
  const float* Alog1 = (const float*)d_in[7];
  const float* D1 = (const float*)d_in[8];
  const float* outp1_w = (const float*)d_in[9];
  const float* in2_w = (const float*)d_in[10];
  const float* conv2_w = (const float*)d_in[11];
  const float* conv2_b = (const float*)d_in[12];
  const float* xp2_w = (const float*)d_in[13];
  const float* dtp2_w = (const float*)d_in[14];
  const float* dtp2_b = (const float*)d_in[15];
  const float* Alog2 = (const float*)d_in[16];
  const float* D2 = (const float*)d_in[17];
  const float* outp2_w = (const float*)d_in[18];
  const float* c1_w = (const float*)d_in[19];
  const float* c1_b = (const float*)d_in[20];
  const float* c2_w = (const float*)d_in[21];
  const float* c2_b = (const float*)d_in[22];
  const float* ln1_g = (const float*)d_in[23];
  const float* ln1_b = (const float*)d_in[24];
  const float* ln2_g = (const float*)d_in[25];
  const float* ln2_b = (const float*)d_in[26];

  const long MB = 1024L * 1024;
  char* wsb = (char*)d_ws;
  bf16* A = (bf16*)(wsb + 0 * MB);
  bf16* B = (bf16*)(wsb + 16 * MB);
  bf16* C = (bf16*)(wsb + 32 * MB);
  bf16* D = (bf16*)(wsb + 48 * MB);
  bf16* E = (bf16*)(wsb + 64 * MB);
  bf16* F = (bf16*)(wsb + 80 * MB);
  float* Bf = (float*)B;   // xln fp32
  float* Cf = (float*)C;   // newx fp32
  float* Af = (float*)A;   // outacc fp32
  bf16* ffn = C;           // 32 MB span C+D, ldc = 2048
  float* P1 = (float*)A;   // xproj partials dir1 (8 MB, xs1 dead post-convT)
  float* P2 = (float*)D;   // xproj partials dir2

  char* ob = (char*)d_out;
  bf16* Wxs = (bf16*)(ob + 0 * MB);    // 2048x512 = 2 MB
  bf16* Wg = (bf16*)(ob + 2 * MB);     // 2048x512 = 2 MB
  bf16* o1b = (bf16*)(ob + 4 * MB);    // 512K (1 MB)
  bf16* o2b = (bf16*)(ob + 5 * MB);
  bf16* c1b = (bf16*)(ob + 6 * MB);    // 1M (2 MB)
  bf16* c2b = (bf16*)(ob + 8 * MB);
  float* xdT1 = (float*)(ob + 10 * MB);  // 64x8192 fp32 (2 MB)
  float* xdT2 = (float*)(ob + 12 * MB);
  float* sd1 = (float*)(ob + 14 * MB);             // 96 KB
  float* sd2 = (float*)(ob + 14 * MB + 131072);    // 96 KB
  bf16* hl1 = (bf16*)(ob + 14 * MB + 262144);      // 768 KB
  bf16* hl2 = (bf16*)(ob + 15 * MB);               // 768 KB

  const long HWN = (long)DIN * DM;   // 524288: one direction's xs (or gate) W

  dim3 blk(256);
  dim3 gP2(2 * DIN / 128, MROWS / 128); // N=2048 merged xs / gate MFMA
  dim3 gM(DM / 128, MROWS / 128);       // N=512 MFMA
  dim3 gF(DFF / 128, MROWS / 128);      // N=2048 MFMA
  dim3 gC(DIN / 64, MROWS / 64);        // convT tiles
  dim3 gXs(MROWS / BN, XSLICE, 2);      // split-K xproj: 1024 blocks
  dim3 gXr(XSZ / 256, 2);               // xred: 2048 x 2 blocks
  dim3 gD(MROWS / BN, DIN / BM);        // dtT: M=1024

  // ---- consolidated weight conversion (1 dispatch) ----
  cvt8_k<<<20480, blk, 0, stream>>>(
      in1_w, in2_w, in1_w + HWN, in2_w + HWN, outp1_w, outp2_w, c1_w, c2_w,
      Wxs, Wxs + HWN, Wg, Wg + HWN, o1b, o2b, c1b, c2b);

  // ---- merged xs projection: xs1 -> A, xs2 (row-flipped) -> D ----
  mgemm_k<MEPI_STORE2, float, bf16><<<gP2, blk, 0, stream>>>(
      x, DM, Wxs, DM, A, D, DIN, nullptr, nullptr, DM);

  // ---- conv + transpose per direction ----
  convT_k<<<gC, blk, 0, stream>>>(A, conv1_w, conv1_b, B);               // xcT1
  convT_k<<<gC, blk, 0, stream>>>(D, conv2_w, conv2_b, E);               // xcT2

  // ---- x-proj: split-K partials (xs buffers now dead) + reduce ----
  xprojs_k<<<gXs, blk, 0, stream>>>(xp1_w, B, P1, xp2_w, E, P2);
  xred_k<<<gXr, blk, 0, stream>>>(P1, xdT1, P2, xdT2);

  // ---- dt-proj per direction ----
  gemmBT_k<EPI_SOFTPLUS_ROW, float, bf16><<<gD, blk, 0, stream>>>(
      dtp1_w, xdT1, C, MROWS, dtp1_b, DTRANK);                           // dtT1
  gemmBT_k<EPI_SOFTPLUS_ROW, float, bf16><<<gD, blk, 0, stream>>>(
      dtp2_w, xdT2, F, MROWS, dtp2_b, DTRANK);                           // dtT2

  // ---- chunked bidirectional scan (4 d per thread) ----
  scan1_k<<<2 * 8 * 3 * 16, blk, 0, stream>>>(
      (const u16*)C, (const u16*)F, (const u16*)B, (const u16*)E,
      xdT1, xdT2, Alog1, Alog2, hl1, hl2, sd1, sd2);
  scan2_k<<<2 * 8 * 4 * 16, blk, 0, stream>>>(
      (const u16*)C, (const u16*)F, (const u16*)B, (const u16*)E,
      xdT1, xdT2, Alog1, Alog2, D1, D2, hl1, hl2, sd1, sd2, A, D);

  // ---- merged gates (in-place over y1 in A, y2 in D) ----
  mgemm_k<MEPI_GATE2, float, bf16><<<gP2, blk, 0, stream>>>(
      x, DM, Wg, DM, A, D, DIN, nullptr, nullptr, DM);

  // ---- merge: newx = y1@W1^T + flip(y2)@W2^T + x -> C (fp32) ----
  mmerge_k<<<gM, blk, 0, stream>>>(A, D, o1b, o2b, x, Cf);

  // ---- LN1: fp32 -> B, bf16 -> E ----
  ln_k<<<MROWS, blk, 0, stream>>>(Cf, ln1_g, ln1_b, Bf, E);

  // ---- FFN (single up, single down) ----
  mgemm_k<MEPI_BIAS_GELU, bf16, bf16><<<gF, blk, 0, stream>>>(
      E, DM, c1b, DM, ffn, nullptr, DFF, c1_b, nullptr, DM);
  mgemm_k<MEPI_BIAS_RES, bf16, float><<<gM, blk, 0, stream>>>(
      ffn, DFF, c2b, DFF, Af, nullptr, DM, c2_b, Bf, DFF);

  // ---- LN2 -> d_out (all d_out scratch dead) ----
  ln_k<<<MROWS, blk, 0, stream>>>(Af, ln2_g, ln2_b, (float*)d_out, nullptr);
}